// Round 2
// baseline (7475.688 us; speedup 1.0000x reference)
//
#include <hip/hip_runtime.h>
#include <cstddef>

#define Bz 32
#define Lz 1024
#define Hz 256
#define Nz (Bz*Lz)          // 32768
#define NHz ((size_t)Nz*Hz) // 8388608
#define BHz (Bz*Hz)         // 8192
#define EPSz 1e-3f
#define NLAYERS 4
#define NCH 64              // gf softmax chunks per batch (Nz/16 blocks, 64 per b)

__device__ inline float sigmoidf(float x){ return 1.f/(1.f+expf(-x)); }

// ---- block-wide (256 threads) sum of (a, b) ----
__device__ inline float2 block_sum2(float a, float b, float* red){
  #pragma unroll
  for (int off=32; off; off>>=1){ a += __shfl_down(a,off,64); b += __shfl_down(b,off,64); }
  int w = threadIdx.x>>6;
  __syncthreads();
  if ((threadIdx.x&63)==0){ red[w]=a; red[4+w]=b; }
  __syncthreads();
  return make_float2(red[0]+red[1]+red[2]+red[3], red[4]+red[5]+red[6]+red[7]);
}

__device__ inline float ln_block(float v, const float* la, const float* lb, int t, float* red){
  float2 ss = block_sum2(v, v*v, red);
  float mean = ss.x*(1.f/Hz);
  float var  = (ss.y - (float)Hz*mean*mean)*(1.f/(Hz-1));
  float isd  = 1.f/(sqrtf(fmaxf(var,0.f))+EPSz);
  return la[t]*(v-mean)*isd + lb[t];
}

// ---- K0: h = h0*mask, c = c0*mask ----
__global__ void k_init(const float4* __restrict__ h0, const float4* __restrict__ c0,
                       const float* __restrict__ mask, float4* __restrict__ h, float4* __restrict__ c){
  int e = blockIdx.x*blockDim.x + threadIdx.x;  // float4 index
  float m = mask[e>>6];
  float4 a = h0[e]; a.x*=m; a.y*=m; a.z*=m; a.w*=m; h[e]=a;
  float4 b = c0[e]; b.x*=m; b.y*=m; b.z*=m; b.w*=m; c[e]=b;
}

// ---- mean over L, two-stage (no atomics) ----
__global__ void k_meanp(const float* __restrict__ x, float* __restrict__ part){
  int b = blockIdx.x, ch = blockIdx.y, t = threadIdx.x;
  const float* p = x + ((size_t)b*Lz + ch*128)*Hz + t;
  float s = 0.f;
  #pragma unroll 4
  for (int l=0;l<128;l++) s += p[(size_t)l*Hz];
  part[(b*8+ch)*Hz + t] = s;
}
__global__ void k_comb8(const float* __restrict__ part, float* __restrict__ o){
  int b = blockIdx.x, t = threadIdx.x;
  float s = 0.f;
  #pragma unroll
  for (int ch=0;ch<8;ch++) s += part[(b*8+ch)*Hz + t];
  o[b*Hz+t] = s*(1.f/Lz);
}

// ---- sentence-level gates + broadcast matvecs.  grid (B, 11) ----
__global__ __launch_bounds__(256) void k_small(
    const float* __restrict__ dh, const float* __restrict__ comb, const float* __restrict__ sent,
    const float* __restrict__ gWx, const float* __restrict__ gWh, const float* __restrict__ gWg,
    const float* __restrict__ gb, const float* __restrict__ Wd_g,
    const float* __restrict__ ln_a, const float* __restrict__ ln_b,
    float* __restrict__ gd, float* __restrict__ gi, float* __restrict__ go,
    float* __restrict__ tgg, float* __restrict__ dhgWx3, float* __restrict__ dhWd){
  int b = blockIdx.x, which = blockIdx.y, t = threadIdx.x;
  __shared__ float sdh[Hz], sse[Hz], sco[Hz];
  __shared__ float red[8];
  sdh[t]=dh[b*Hz+t]; sse[t]=sent[b*Hz+t]; sco[t]=comb[b*Hz+t];
  __syncthreads();
  float acc=0.f;
  if (which < 3){
    const float* W0 = gWx + which*Hz*Hz;
    const float* W1 = gWg + which*Hz*Hz;
    const float* W2 = gWh + which*Hz*Hz;
    for (int k=0;k<Hz;k++) acc += sdh[k]*W0[k*Hz+t] + sse[k]*W1[k*Hz+t] + sco[k]*W2[k*Hz+t];
    if (which==0){
      float r = ln_block(acc + gb[0*Hz+t], ln_a+6*Hz, ln_b+6*Hz, t, red);
      gd[b*Hz+t] = sigmoidf(r);
    } else if (which==1){
      float r = ln_block(acc, ln_a+9*Hz, ln_b+9*Hz, t, red);
      gi[b*Hz+t] = sigmoidf(r + gb[1*Hz+t]);
    } else {
      float r = ln_block(acc + gb[2*Hz+t], ln_a+7*Hz, ln_b+7*Hz, t, red);
      go[b*Hz+t] = sigmoidf(r);
    }
  } else if (which == 3){
    const float* W = gWg + 3*Hz*Hz;
    for (int k=0;k<Hz;k++) acc += sse[k]*W[k*Hz+t];
    float r = ln_block(acc, ln_a+10*Hz, ln_b+10*Hz, t, red);
    tgg[b*Hz+t] = tanhf(r);
  } else if (which == 4){
    const float* W = gWx + 3*Hz*Hz;
    for (int k=0;k<Hz;k++) acc += sdh[k]*W[k*Hz+t];
    dhgWx3[b*Hz+t] = acc;
  } else {
    int g = which-5;
    const float* W = Wd_g + g*Hz*Hz;
    for (int k=0;k<Hz;k++) acc += sdh[k]*W[k*Hz+t];
    dhWd[(g*Bz + b)*Hz + t] = acc;
  }
}

// ---- gf GEMM + LN + sigmoid + msm + online-softmax partials.  16 rows/block ----
__global__ __launch_bounds__(256) void k_gfsoft(
    const float* __restrict__ h, const float* __restrict__ c,
    const float* __restrict__ dhgWx3, const float* __restrict__ gWh3, const float* __restrict__ gb3,
    const float* __restrict__ mask, const float* __restrict__ lna8, const float* __restrict__ lnb8,
    float* __restrict__ pm, float* __restrict__ ps, float* __restrict__ pn){
  __shared__ __align__(16) float As[16][260];
  __shared__ float smask[16], s_s[16], s_q[16];
  int t = threadIdx.x;
  int n0 = blockIdx.x*16;
  int b = n0 >> 10;
  if (t < 16) smask[t] = mask[n0 + t];
  #pragma unroll
  for (int p=0;p<4;p++){
    int row = p*4 + (t>>6);
    int col = (t&63)*4;
    *(float4*)&As[row][col] = *(const float4*)&h[(size_t)(n0+row)*Hz + col];
  }
  float acc[16];
  #pragma unroll
  for (int r=0;r<16;r++) acc[r]=0.f;
  __syncthreads();
  const float* Bp = gWh3 + t;
  for (int k=0;k<256;k+=2){
    float2 a2[16];
    #pragma unroll
    for (int r=0;r<16;r++) a2[r] = *(const float2*)&As[r][k];
    float b0 = Bp[(size_t)k*Hz];
    float b1 = Bp[(size_t)(k+1)*Hz];
    #pragma unroll
    for (int r=0;r<16;r++) acc[r] = fmaf(a2[r].x, b0, fmaf(a2[r].y, b1, acc[r]));
  }
  float wd = dhgWx3[b*Hz + t];
  float bias = gb3[t];
  __syncthreads();
  #pragma unroll
  for (int r=0;r<16;r++){ float v = acc[r] + smask[r]*wd + bias; acc[r]=v; As[r][t]=v; }
  __syncthreads();
  int rr = t>>4, j = t&15;
  float s=0.f, q=0.f;
  #pragma unroll
  for (int i=0;i<16;i++){ float x = As[rr][j+16*i]; s+=x; q+=x*x; }
  #pragma unroll
  for (int off=8; off; off>>=1){ s += __shfl_down(s,off,16); q += __shfl_down(q,off,16); }
  if (j==0){ s_s[rr]=s; s_q[rr]=q; }
  __syncthreads();
  float la = lna8[t], lb = lnb8[t];
  float gfv[16];
  float m = -1e30f;
  #pragma unroll
  for (int r=0;r<16;r++){
    float mean = s_s[r]*(1.f/Hz);
    float var  = (s_q[r] - (float)Hz*mean*mean)*(1.f/(Hz-1));
    float isd  = 1.f/(sqrtf(fmaxf(var,0.f))+EPSz);
    float gv = sigmoidf(la*(acc[r]-mean)*isd + lb) + (smask[r]*1e25f - 1e25f);
    gfv[r] = gv;
    m = fmaxf(m, gv);
  }
  float se=0.f, num=0.f;
  #pragma unroll
  for (int r=0;r<16;r++){
    float e = expf(gfv[r]-m);
    se += e;
    num += e * c[(size_t)(n0+r)*Hz + t];
  }
  int ch = blockIdx.x & (NCH-1);
  int idx = (b*NCH + ch)*Hz + t;
  pm[idx]=m; ps[idx]=se; pn[idx]=num;
}

// ---- combine partials + gd/gi slots -> dc_new, dh_new ----
__global__ void k_soft_comb(const float* __restrict__ pm, const float* __restrict__ ps,
    const float* __restrict__ pn,
    const float* __restrict__ gd, const float* __restrict__ gi, const float* __restrict__ go,
    const float* __restrict__ tgg, const float* __restrict__ dc,
    float* __restrict__ dc_new, float* __restrict__ dh_new){
  int b = blockIdx.x, t = threadIdx.x;
  float vgd = gd[b*Hz+t], vgi = gi[b*Hz+t];
  float m = fmaxf(vgd, vgi);
  for (int ch=0; ch<NCH; ch++) m = fmaxf(m, pm[(b*NCH+ch)*Hz + t]);
  float ed = expf(vgd - m), ei = expf(vgi - m);
  float s  = ed + ei;
  float num = ed*dc[b*Hz+t] + ei*tgg[b*Hz+t];
  for (int ch=0; ch<NCH; ch++){
    int idx = (b*NCH+ch)*Hz + t;
    float e = expf(pm[idx] - m);
    s   += ps[idx]*e;
    num += pn[idx]*e;
  }
  float dcn = num/s;
  dc_new[b*Hz+t] = dcn;
  dh_new[b*Hz+t] = go[b*Hz+t]*tanhf(dcn);
}

// ---- fused: 6-gate GEMM (X(Nx1024)@W per gate) + LN + sigmoid + 5-softmax + cell update.
//      16 rows x 256 cols x 6 gates per block; column-per-thread; weights streamed (L2). ----
__global__ __launch_bounds__(256) void k_fused(
    const float* __restrict__ word, const float* __restrict__ h, const float* __restrict__ c,
    const float* __restrict__ mask,
    const float* __restrict__ Wx, const float* __restrict__ Wh, const float* __restrict__ Wi,
    const float* __restrict__ dhWd, const float* __restrict__ b_g,
    const float* __restrict__ ln_a, const float* __restrict__ ln_b,
    const float* __restrict__ dc,
    float* __restrict__ hn, float* __restrict__ cn){
  __shared__ __align__(16) float As[16][260];
  __shared__ float smask[16], s_s[16], s_q[16];
  int t = threadIdx.x;
  int n0 = blockIdx.x*16;
  int b = n0 >> 10;
  if (t < 16) smask[t] = mask[n0 + t];
  float acc[6][16];
  #pragma unroll
  for (int g=0;g<6;g++)
    #pragma unroll
    for (int r=0;r<16;r++) acc[g][r]=0.f;

  for (int seg=0; seg<4; ++seg){
    __syncthreads();
    #pragma unroll
    for (int p=0;p<4;p++){
      int row = p*4 + (t>>6);
      int n = n0 + row;
      int col = (t&63)*4;
      float4 v = make_float4(0.f,0.f,0.f,0.f);
      if (seg==0){
        v = *(const float4*)&word[(size_t)n*Hz+col];
        float m = mask[n]; v.x*=m; v.y*=m; v.z*=m; v.w*=m;
      } else if (seg==1){
        if ((n&1023)!=0)    v = *(const float4*)&h[(size_t)(n-1)*Hz+col];
      } else if (seg==2){
        if ((n&1023)!=1023) v = *(const float4*)&h[(size_t)(n+1)*Hz+col];
      } else {
        v = *(const float4*)&h[(size_t)n*Hz+col];
      }
      *(float4*)&As[row][col] = v;
    }
    __syncthreads();
    const float* Bg[6];
    #pragma unroll
    for (int g=0;g<6;g++){
      const float* base = (seg==0) ? (Wx + (size_t)g*65536)
                        : (seg==1) ? (Wh + (size_t)g*131072)
                        : (seg==2) ? (Wh + (size_t)g*131072 + 65536)
                                   : (Wi + (size_t)g*65536);
      Bg[g] = base + t;
    }
    for (int k=0;k<256;k+=2){
      float2 a2[16];
      #pragma unroll
      for (int r=0;r<16;r++) a2[r] = *(const float2*)&As[r][k];
      #pragma unroll
      for (int g=0;g<6;g++){
        float b0 = Bg[g][(size_t)k*Hz];
        float b1 = Bg[g][(size_t)(k+1)*Hz];
        #pragma unroll
        for (int r=0;r<16;r++) acc[g][r] = fmaf(a2[r].x, b0, fmaf(a2[r].y, b1, acc[g][r]));
      }
    }
  }

  // epilogue: per gate, add dhWd*mask + bias, LN over the row, sigmoid
  #pragma unroll 1
  for (int g=0; g<6; g++){
    float wd = dhWd[(g*Bz + b)*Hz + t];
    float bg = b_g[g*Hz + t];
    __syncthreads();
    #pragma unroll
    for (int r=0;r<16;r++){ float v = acc[g][r] + smask[r]*wd + bg; acc[g][r]=v; As[r][t]=v; }
    __syncthreads();
    int rr = t>>4, j = t&15;
    float s=0.f, q=0.f;
    #pragma unroll
    for (int i=0;i<16;i++){ float x = As[rr][j+16*i]; s+=x; q+=x*x; }
    #pragma unroll
    for (int off=8; off; off>>=1){ s += __shfl_down(s,off,16); q += __shfl_down(q,off,16); }
    if (j==0){ s_s[rr]=s; s_q[rr]=q; }
    __syncthreads();
    float la = ln_a[g*Hz+t], lb = ln_b[g*Hz+t];
    #pragma unroll
    for (int r=0;r<16;r++){
      float mean = s_s[r]*(1.f/Hz);
      float var  = (s_q[r] - (float)Hz*mean*mean)*(1.f/(Hz-1));
      float isd  = 1.f/(sqrtf(fmaxf(var,0.f))+EPSz);
      acc[g][r] = sigmoidf(la*(acc[g][r]-mean)*isd + lb);
    }
  }

  // 5-way softmax over gates 0..4 + cell update
  float tdc_col = dc[b*Hz + t];
  #pragma unroll 1
  for (int r=0;r<16;r++){
    int n = n0 + r;
    int l = n & 1023;
    float msk = smask[r];
    float g0=acc[0][r], g1=acc[1][r], g2=acc[2][r], g3=acc[3][r], g4=acc[4][r];
    float m5 = fmaxf(fmaxf(fmaxf(g0,g1),fmaxf(g2,g3)),g4);
    float e0=expf(g0-m5), e1=expf(g1-m5), e2=expf(g2-m5), e3=expf(g3-m5), e4=expf(g4-m5);
    float inv = 1.f/(e0+e1+e2+e3+e4);
    float cb = (l==0)    ? 0.f : c[(size_t)(n-1)*Hz + t];
    float ca = (l==1023) ? 0.f : c[(size_t)(n+1)*Hz + t];
    float cv = c[(size_t)n*Hz + t];
    float em = word[(size_t)n*Hz + t]*msk;
    float td = tdc_col*msk;
    float cnew = (cb*e0 + ca*e1 + em*e2 + td*e3 + cv*e4)*inv;
    float hv = acc[5][r]*tanhf(cnew);
    cn[(size_t)n*Hz + t] = cnew*msk;
    hn[(size_t)n*Hz + t] = hv*msk;
  }
}

extern "C" void kernel_launch(void* const* d_in, const int* in_sizes, int n_in,
                              void* d_out, int out_size, void* d_ws, size_t ws_size,
                              hipStream_t stream) {
  const float* word  = (const float*)d_in[0];
  const float* sent  = (const float*)d_in[1];
  const float* mask  = (const float*)d_in[2];
  const float* h0    = (const float*)d_in[3];
  const float* c0    = (const float*)d_in[4];
  const float* Wx_g  = (const float*)d_in[5];
  const float* Wh_g  = (const float*)d_in[6];
  const float* Wi_g  = (const float*)d_in[7];
  const float* Wd_g  = (const float*)d_in[8];
  const float* b_g   = (const float*)d_in[9];
  const float* gWx   = (const float*)d_in[10];
  const float* gWh   = (const float*)d_in[11];
  const float* gWg   = (const float*)d_in[12];
  const float* gb    = (const float*)d_in[13];
  const float* ln_a  = (const float*)d_in[14];
  const float* ln_b  = (const float*)d_in[15];
  float* out = (float*)d_out;

  float* w = (float*)d_ws;
  float* h_a = w;              w += NHz;
  float* h_b = w;              w += NHz;
  float* c_a = w;              w += NHz;
  float* c_b = w;              w += NHz;
  float* dh_a = w;             w += BHz;
  float* dh_b = w;             w += BHz;
  float* dc_a = w;             w += BHz;
  float* dc_b = w;             w += BHz;
  float* comb = w;             w += BHz;
  float* gd = w;               w += BHz;
  float* gi_ = w;              w += BHz;
  float* go_ = w;              w += BHz;
  float* tgg = w;              w += BHz;
  float* dhgWx3 = w;           w += BHz;
  float* dhWd = w;             w += 6*BHz;
  float* pmean = w;            w += 8*BHz;
  float* pm = w;               w += (size_t)Bz*NCH*Hz;
  float* ps = w;               w += (size_t)Bz*NCH*Hz;
  float* pn = w;               w += (size_t)Bz*NCH*Hz;
  // total ~35.3M floats ~141 MB

  k_init<<<(int)(NHz/4/256), 256, 0, stream>>>((const float4*)h0, (const float4*)c0, mask,
                                               (float4*)h_a, (float4*)c_a);
  k_meanp<<<dim3(Bz,8), 256, 0, stream>>>(h_a, pmean);
  k_comb8<<<Bz, 256, 0, stream>>>(pmean, dh_a);
  k_meanp<<<dim3(Bz,8), 256, 0, stream>>>(c_a, pmean);
  k_comb8<<<Bz, 256, 0, stream>>>(pmean, dc_a);

  float* hc=h_a; float* cc=c_a; float* hn=h_b; float* cn=c_b;
  float* dhc=dh_a; float* dcc=dc_a; float* dhn=dh_b; float* dcn=dc_b;

  for (int layer=0; layer<NLAYERS; ++layer){
    k_meanp<<<dim3(Bz,8), 256, 0, stream>>>(hc, pmean);
    k_comb8<<<Bz, 256, 0, stream>>>(pmean, comb);
    k_small<<<dim3(Bz,11), 256, 0, stream>>>(dhc, comb, sent, gWx, gWh, gWg, gb, Wd_g,
                                             ln_a, ln_b, gd, gi_, go_, tgg, dhgWx3, dhWd);
    k_gfsoft<<<Nz/16, 256, 0, stream>>>(hc, cc, dhgWx3, gWh + 3*Hz*Hz, gb + 3*Hz, mask,
                                        ln_a + 8*Hz, ln_b + 8*Hz, pm, ps, pn);
    k_soft_comb<<<Bz, 256, 0, stream>>>(pm, ps, pn, gd, gi_, go_, tgg, dcc, dcn, dhn);
    float* hout = (layer == NLAYERS-1) ? out : hn;
    k_fused<<<Nz/16, 256, 0, stream>>>(word, hc, cc, mask, Wx_g, Wh_g, Wi_g,
                                       dhWd, b_g, ln_a, ln_b, dcc, hout, cn);
    float* tmp;
    tmp=hc; hc=hn; hn=tmp;
    tmp=cc; cc=cn; cn=tmp;
    tmp=dhc; dhc=dhn; dhn=tmp;
    tmp=dcc; dcc=dcn; dcn=tmp;
  }
  (void)in_sizes; (void)n_in; (void)out_size; (void)ws_size;
}

// Round 3
// 3321.388 us; speedup vs baseline: 2.2508x; 2.2508x over previous
//
#include <hip/hip_runtime.h>
#include <cstddef>

#define Bz 32
#define Lz 1024
#define Hz 256
#define Nz (Bz*Lz)          // 32768
#define NHz ((size_t)Nz*Hz) // 8388608
#define BHz (Bz*Hz)         // 8192
#define EPSz 1e-3f
#define NLAYERS 4
#define NCH 64              // gf softmax chunks per batch

typedef __bf16 bf8_t __attribute__((ext_vector_type(8)));
typedef __bf16 bf4_t __attribute__((ext_vector_type(4)));
typedef float  f4_t  __attribute__((ext_vector_type(4)));

__device__ inline float sigmoidf(float x){ return 1.f/(1.f+expf(-x)); }

// ---- block-wide (256 threads) sum of (a, b) ----
__device__ inline float2 block_sum2(float a, float b, float* red){
  #pragma unroll
  for (int off=32; off; off>>=1){ a += __shfl_down(a,off,64); b += __shfl_down(b,off,64); }
  int w = threadIdx.x>>6;
  __syncthreads();
  if ((threadIdx.x&63)==0){ red[w]=a; red[4+w]=b; }
  __syncthreads();
  return make_float2(red[0]+red[1]+red[2]+red[3], red[4]+red[5]+red[6]+red[7]);
}

__device__ inline float ln_block(float v, const float* la, const float* lb, int t, float* red){
  float2 ss = block_sum2(v, v*v, red);
  float mean = ss.x*(1.f/Hz);
  float var  = (ss.y - (float)Hz*mean*mean)*(1.f/(Hz-1));
  float isd  = 1.f/(sqrtf(fmaxf(var,0.f))+EPSz);
  return la[t]*(v-mean)*isd + lb[t];
}

// ---- K0: h = h0*mask, c = c0*mask ----
__global__ void k_init(const float4* __restrict__ h0, const float4* __restrict__ c0,
                       const float* __restrict__ mask, float4* __restrict__ h, float4* __restrict__ c){
  int e = blockIdx.x*blockDim.x + threadIdx.x;
  float m = mask[e>>6];
  float4 a = h0[e]; a.x*=m; a.y*=m; a.z*=m; a.w*=m; h[e]=a;
  float4 b = c0[e]; b.x*=m; b.y*=m; b.z*=m; b.w*=m; c[e]=b;
}

// ---- fp32 -> bf16 (4 elems/thread) ----
__global__ void k_tobf16(const float4* __restrict__ in, bf4_t* __restrict__ out){
  int i = blockIdx.x*blockDim.x + threadIdx.x;
  float4 v = in[i];
  bf4_t o;
  o[0]=(__bf16)v.x; o[1]=(__bf16)v.y; o[2]=(__bf16)v.z; o[3]=(__bf16)v.w;
  out[i] = o;
}

// ---- word*mask -> bf16 ----
__global__ void k_toxe(const float4* __restrict__ word, const float* __restrict__ mask,
                       bf4_t* __restrict__ out){
  int i = blockIdx.x*blockDim.x + threadIdx.x;
  float m = mask[i>>6];
  float4 v = word[i];
  bf4_t o;
  o[0]=(__bf16)(v.x*m); o[1]=(__bf16)(v.y*m); o[2]=(__bf16)(v.z*m); o[3]=(__bf16)(v.w*m);
  out[i] = o;
}

// ---- pack 6-gate weights into MFMA B-fragment order:
//      Wp[(((g*32+kb)*256 + c)*4 + p)*8 + j] = W_seg[k_local][c], k_global=kb*32+p*8+j ----
__global__ void k_packW(const float* __restrict__ Wx, const float* __restrict__ Wh,
                        const float* __restrict__ Wi, __bf16* __restrict__ Wp){
  int tid = blockIdx.x*256 + threadIdx.x;     // 196608 threads, 8 elems each
  int p = tid & 3, c = (tid>>2) & 255, kb = (tid>>10) & 31, g = tid>>15;
  int seg = kb >> 3;
  int kl  = (kb*32 + p*8) & 255;
  const float* src = (seg==0) ? Wx + ((size_t)g*256 + kl)*256 + c
                   : (seg==1) ? Wh + ((size_t)g*512 + kl)*256 + c
                   : (seg==2) ? Wh + ((size_t)g*512 + 256 + kl)*256 + c
                              : Wi + ((size_t)g*256 + kl)*256 + c;
  __bf16* dst = Wp + (size_t)tid*8;
  #pragma unroll
  for (int j=0;j<8;j++) dst[j] = (__bf16)src[(size_t)j*256];
}

// ---- mean over L, two-stage ----
__global__ void k_meanp(const float* __restrict__ x, float* __restrict__ part){
  int b = blockIdx.x, ch = blockIdx.y, t = threadIdx.x;
  const float* p = x + ((size_t)b*Lz + ch*128)*Hz + t;
  float s = 0.f;
  #pragma unroll 4
  for (int l=0;l<128;l++) s += p[(size_t)l*Hz];
  part[(b*8+ch)*Hz + t] = s;
}
__global__ void k_comb8(const float* __restrict__ part, float* __restrict__ o){
  int b = blockIdx.x, t = threadIdx.x;
  float s = 0.f;
  #pragma unroll
  for (int ch=0;ch<8;ch++) s += part[(b*8+ch)*Hz + t];
  o[b*Hz+t] = s*(1.f/Lz);
}

// ---- sentence-level gates + broadcast matvecs.  grid (B, 11) ----
__global__ __launch_bounds__(256) void k_small(
    const float* __restrict__ dh, const float* __restrict__ comb, const float* __restrict__ sent,
    const float* __restrict__ gWx, const float* __restrict__ gWh, const float* __restrict__ gWg,
    const float* __restrict__ gb, const float* __restrict__ Wd_g,
    const float* __restrict__ ln_a, const float* __restrict__ ln_b,
    float* __restrict__ gd, float* __restrict__ gi, float* __restrict__ go,
    float* __restrict__ tgg, float* __restrict__ dhgWx3, float* __restrict__ dhWd){
  int b = blockIdx.x, which = blockIdx.y, t = threadIdx.x;
  __shared__ float sdh[Hz], sse[Hz], sco[Hz];
  __shared__ float red[8];
  sdh[t]=dh[b*Hz+t]; sse[t]=sent[b*Hz+t]; sco[t]=comb[b*Hz+t];
  __syncthreads();
  float acc=0.f;
  if (which < 3){
    const float* W0 = gWx + which*Hz*Hz;
    const float* W1 = gWg + which*Hz*Hz;
    const float* W2 = gWh + which*Hz*Hz;
    for (int k=0;k<Hz;k++) acc += sdh[k]*W0[k*Hz+t] + sse[k]*W1[k*Hz+t] + sco[k]*W2[k*Hz+t];
    if (which==0){
      float r = ln_block(acc + gb[0*Hz+t], ln_a+6*Hz, ln_b+6*Hz, t, red);
      gd[b*Hz+t] = sigmoidf(r);
    } else if (which==1){
      float r = ln_block(acc, ln_a+9*Hz, ln_b+9*Hz, t, red);
      gi[b*Hz+t] = sigmoidf(r + gb[1*Hz+t]);
    } else {
      float r = ln_block(acc + gb[2*Hz+t], ln_a+7*Hz, ln_b+7*Hz, t, red);
      go[b*Hz+t] = sigmoidf(r);
    }
  } else if (which == 3){
    const float* W = gWg + 3*Hz*Hz;
    for (int k=0;k<Hz;k++) acc += sse[k]*W[k*Hz+t];
    float r = ln_block(acc, ln_a+10*Hz, ln_b+10*Hz, t, red);
    tgg[b*Hz+t] = tanhf(r);
  } else if (which == 4){
    const float* W = gWx + 3*Hz*Hz;
    for (int k=0;k<Hz;k++) acc += sdh[k]*W[k*Hz+t];
    dhgWx3[b*Hz+t] = acc;
  } else {
    int g = which-5;
    const float* W = Wd_g + g*Hz*Hz;
    for (int k=0;k<Hz;k++) acc += sdh[k]*W[k*Hz+t];
    dhWd[(g*Bz + b)*Hz + t] = acc;
  }
}

// ---- gf GEMM + LN + sigmoid + msm + online-softmax partials.  16 rows/block ----
__global__ __launch_bounds__(256) void k_gfsoft(
    const float* __restrict__ h, const float* __restrict__ c,
    const float* __restrict__ dhgWx3, const float* __restrict__ gWh3, const float* __restrict__ gb3,
    const float* __restrict__ mask, const float* __restrict__ lna8, const float* __restrict__ lnb8,
    float* __restrict__ pm, float* __restrict__ ps, float* __restrict__ pn){
  __shared__ __align__(16) float As[16][260];
  __shared__ float smask[16], s_s[16], s_q[16];
  int t = threadIdx.x;
  int n0 = blockIdx.x*16;
  int b = n0 >> 10;
  if (t < 16) smask[t] = mask[n0 + t];
  #pragma unroll
  for (int p=0;p<4;p++){
    int row = p*4 + (t>>6);
    int col = (t&63)*4;
    *(float4*)&As[row][col] = *(const float4*)&h[(size_t)(n0+row)*Hz + col];
  }
  float acc[16];
  #pragma unroll
  for (int r=0;r<16;r++) acc[r]=0.f;
  __syncthreads();
  const float* Bp = gWh3 + t;
  for (int k=0;k<256;k+=2){
    float2 a2[16];
    #pragma unroll
    for (int r=0;r<16;r++) a2[r] = *(const float2*)&As[r][k];
    float b0 = Bp[(size_t)k*Hz];
    float b1 = Bp[(size_t)(k+1)*Hz];
    #pragma unroll
    for (int r=0;r<16;r++) acc[r] = fmaf(a2[r].x, b0, fmaf(a2[r].y, b1, acc[r]));
  }
  float wd = dhgWx3[b*Hz + t];
  float bias = gb3[t];
  __syncthreads();
  #pragma unroll
  for (int r=0;r<16;r++){ float v = acc[r] + smask[r]*wd + bias; acc[r]=v; As[r][t]=v; }
  __syncthreads();
  int rr = t>>4, j = t&15;
  float s=0.f, q=0.f;
  #pragma unroll
  for (int i=0;i<16;i++){ float x = As[rr][j+16*i]; s+=x; q+=x*x; }
  #pragma unroll
  for (int off=8; off; off>>=1){ s += __shfl_down(s,off,16); q += __shfl_down(q,off,16); }
  if (j==0){ s_s[rr]=s; s_q[rr]=q; }
  __syncthreads();
  float la = lna8[t], lb = lnb8[t];
  float gfv[16];
  float m = -1e30f;
  #pragma unroll
  for (int r=0;r<16;r++){
    float mean = s_s[r]*(1.f/Hz);
    float var  = (s_q[r] - (float)Hz*mean*mean)*(1.f/(Hz-1));
    float isd  = 1.f/(sqrtf(fmaxf(var,0.f))+EPSz);
    float gv = sigmoidf(la*(acc[r]-mean)*isd + lb) + (smask[r]*1e25f - 1e25f);
    gfv[r] = gv;
    m = fmaxf(m, gv);
  }
  float se=0.f, num=0.f;
  #pragma unroll
  for (int r=0;r<16;r++){
    float e = expf(gfv[r]-m);
    se += e;
    num += e * c[(size_t)(n0+r)*Hz + t];
  }
  int ch = blockIdx.x & (NCH-1);
  int idx = (b*NCH + ch)*Hz + t;
  pm[idx]=m; ps[idx]=se; pn[idx]=num;
}

// ---- combine partials + gd/gi slots -> dc_new, dh_new ----
__global__ void k_soft_comb(const float* __restrict__ pm, const float* __restrict__ ps,
    const float* __restrict__ pn,
    const float* __restrict__ gd, const float* __restrict__ gi, const float* __restrict__ go,
    const float* __restrict__ tgg, const float* __restrict__ dc,
    float* __restrict__ dc_new, float* __restrict__ dh_new){
  int b = blockIdx.x, t = threadIdx.x;
  float vgd = gd[b*Hz+t], vgi = gi[b*Hz+t];
  float m = fmaxf(vgd, vgi);
  for (int ch=0; ch<NCH; ch++) m = fmaxf(m, pm[(b*NCH+ch)*Hz + t]);
  float ed = expf(vgd - m), ei = expf(vgi - m);
  float s  = ed + ei;
  float num = ed*dc[b*Hz+t] + ei*tgg[b*Hz+t];
  for (int ch=0; ch<NCH; ch++){
    int idx = (b*NCH+ch)*Hz + t;
    float e = expf(pm[idx] - m);
    s   += ps[idx]*e;
    num += pn[idx]*e;
  }
  float dcn = num/s;
  dc_new[b*Hz+t] = dcn;
  dh_new[b*Hz+t] = go[b*Hz+t]*tanhf(dcn);
}

// ---- fused MFMA: 6-gate GEMM + LN + sigmoid + 5-softmax + cell update.
//      16 rows x 256 cols x 6 gates per block; wave w owns cols [w*64, w*64+64). ----
__global__ __launch_bounds__(256) void k_fmfma(
    const __bf16* __restrict__ xe_bf, const __bf16* __restrict__ h_bf,
    const __bf16* __restrict__ Wp,
    const float* __restrict__ word, const float* __restrict__ c, const float* __restrict__ mask,
    const float* __restrict__ dhWd, const float* __restrict__ b_g,
    const float* __restrict__ ln_a, const float* __restrict__ ln_b,
    const float* __restrict__ dc,
    float* __restrict__ hn, float* __restrict__ cn){
  __shared__ float smask[16];
  __shared__ float sred_s[4][6][16];
  __shared__ float sred_q[4][6][16];
  int t = threadIdx.x;
  int n0 = blockIdx.x*16;
  int b = n0 >> 10;
  if (t < 16) smask[t] = mask[n0 + t];
  __syncthreads();

  int w = t>>6, lane = t&63;
  int m16 = lane&15, p = lane>>4;
  int nA = n0 + m16;            // A-row for this lane
  int lA = nA & 1023;
  int col_base = w*64 + m16;
  size_t laneoff = (size_t)(col_base*4 + p)*8;

  f4_t acc[6][4];
  #pragma unroll
  for (int g=0;g<6;g++)
    #pragma unroll
    for (int tc=0;tc<4;tc++) acc[g][tc] = (f4_t){0.f,0.f,0.f,0.f};

  bf8_t az;
  #pragma unroll
  for (int j=0;j<8;j++) az[j] = (__bf16)0.f;

  #pragma unroll 1
  for (int seg=0; seg<4; ++seg){
    #pragma unroll 2
    for (int kq=0; kq<8; ++kq){
      int kb = seg*8 + kq;
      int koff = kq*32 + p*8;   // bf16 offset within the 256-wide segment row
      bf8_t a = az;
      if (seg==0)      a = *(const bf8_t*)(xe_bf + (size_t)nA*Hz + koff);
      else if (seg==3) a = *(const bf8_t*)(h_bf + (size_t)nA*Hz + koff);
      else if (seg==1){ if (lA!=0)    a = *(const bf8_t*)(h_bf + (size_t)(nA-1)*Hz + koff); }
      else            { if (lA!=1023) a = *(const bf8_t*)(h_bf + (size_t)(nA+1)*Hz + koff); }
      const __bf16* wb = Wp + (size_t)kb*8192 + laneoff;
      #pragma unroll
      for (int g=0; g<6; ++g){
        #pragma unroll
        for (int tc=0; tc<4; ++tc){
          bf8_t bf = *(const bf8_t*)(wb + (size_t)g*262144 + tc*512);
          acc[g][tc] = __builtin_amdgcn_mfma_f32_16x16x32_bf16(a, bf, acc[g][tc], 0, 0, 0);
        }
      }
    }
  }

  // ---- epilogue: + dhWd*mask + bias, LN per row, sigmoid ----
  #pragma unroll 1
  for (int g=0; g<6; ++g){
    float s_r[4] = {0.f,0.f,0.f,0.f};
    float q_r[4] = {0.f,0.f,0.f,0.f};
    #pragma unroll
    for (int tc=0; tc<4; ++tc){
      int col = w*64 + tc*16 + m16;
      float wd = dhWd[(g*Bz + b)*Hz + col];
      float bg = b_g[g*Hz + col];
      #pragma unroll
      for (int reg=0; reg<4; ++reg){
        float x = acc[g][tc][reg] + smask[p*4+reg]*wd + bg;
        acc[g][tc][reg] = x;
        s_r[reg] += x; q_r[reg] += x*x;
      }
    }
    #pragma unroll
    for (int off=1; off<16; off<<=1){
      #pragma unroll
      for (int reg=0; reg<4; ++reg){
        s_r[reg] += __shfl_xor(s_r[reg], off, 64);
        q_r[reg] += __shfl_xor(q_r[reg], off, 64);
      }
    }
    if (m16==0){
      #pragma unroll
      for (int reg=0; reg<4; ++reg){
        sred_s[w][g][p*4+reg] = s_r[reg];
        sred_q[w][g][p*4+reg] = q_r[reg];
      }
    }
  }
  __syncthreads();

  #pragma unroll 1
  for (int g=0; g<6; ++g){
    float mean_r[4], isd_r[4];
    #pragma unroll
    for (int reg=0; reg<4; ++reg){
      int row = p*4+reg;
      float ss = sred_s[0][g][row]+sred_s[1][g][row]+sred_s[2][g][row]+sred_s[3][g][row];
      float qq = sred_q[0][g][row]+sred_q[1][g][row]+sred_q[2][g][row]+sred_q[3][g][row];
      float mean = ss*(1.f/Hz);
      float var  = (qq - (float)Hz*mean*mean)*(1.f/(Hz-1));
      mean_r[reg] = mean;
      isd_r[reg]  = 1.f/(sqrtf(fmaxf(var,0.f))+EPSz);
    }
    #pragma unroll
    for (int tc=0; tc<4; ++tc){
      int col = w*64 + tc*16 + m16;
      float la = ln_a[g*Hz+col], lb = ln_b[g*Hz+col];
      #pragma unroll
      for (int reg=0; reg<4; ++reg){
        acc[g][tc][reg] = sigmoidf(la*(acc[g][tc][reg]-mean_r[reg])*isd_r[reg] + lb);
      }
    }
  }

  // ---- 5-way softmax over gates + cell update ----
  #pragma unroll 1
  for (int tc=0; tc<4; ++tc){
    int col = w*64 + tc*16 + m16;
    float tdc = dc[b*Hz + col];
    #pragma unroll
    for (int reg=0; reg<4; ++reg){
      int n2 = n0 + p*4 + reg;
      int l2 = n2 & 1023;
      float msk = smask[p*4+reg];
      float g0=acc[0][tc][reg], g1=acc[1][tc][reg], g2=acc[2][tc][reg],
            g3=acc[3][tc][reg], g4=acc[4][tc][reg];
      float m5 = fmaxf(fmaxf(fmaxf(g0,g1),fmaxf(g2,g3)),g4);
      float e0=expf(g0-m5), e1=expf(g1-m5), e2=expf(g2-m5), e3=expf(g3-m5), e4=expf(g4-m5);
      float inv = 1.f/(e0+e1+e2+e3+e4);
      float cb = (l2==0)    ? 0.f : c[(size_t)(n2-1)*Hz + col];
      float ca = (l2==1023) ? 0.f : c[(size_t)(n2+1)*Hz + col];
      float cv = c[(size_t)n2*Hz + col];
      float em = word[(size_t)n2*Hz + col]*msk;
      float td = tdc*msk;
      float cnew = (cb*e0 + ca*e1 + em*e2 + td*e3 + cv*e4)*inv;
      float hv = acc[5][tc][reg]*tanhf(cnew);
      cn[(size_t)n2*Hz + col] = cnew*msk;
      hn[(size_t)n2*Hz + col] = hv*msk;
    }
  }
}

extern "C" void kernel_launch(void* const* d_in, const int* in_sizes, int n_in,
                              void* d_out, int out_size, void* d_ws, size_t ws_size,
                              hipStream_t stream) {
  const float* word  = (const float*)d_in[0];
  const float* sent  = (const float*)d_in[1];
  const float* mask  = (const float*)d_in[2];
  const float* h0    = (const float*)d_in[3];
  const float* c0    = (const float*)d_in[4];
  const float* Wx_g  = (const float*)d_in[5];
  const float* Wh_g  = (const float*)d_in[6];
  const float* Wi_g  = (const float*)d_in[7];
  const float* Wd_g  = (const float*)d_in[8];
  const float* b_g   = (const float*)d_in[9];
  const float* gWx   = (const float*)d_in[10];
  const float* gWh   = (const float*)d_in[11];
  const float* gWg   = (const float*)d_in[12];
  const float* gb    = (const float*)d_in[13];
  const float* ln_a  = (const float*)d_in[14];
  const float* ln_b  = (const float*)d_in[15];
  float* out = (float*)d_out;

  float* w = (float*)d_ws;
  float* h_a = w;              w += NHz;
  float* h_b = w;              w += NHz;
  float* c_a = w;              w += NHz;
  float* c_b = w;              w += NHz;
  float* dh_a = w;             w += BHz;
  float* dh_b = w;             w += BHz;
  float* dc_a = w;             w += BHz;
  float* dc_b = w;             w += BHz;
  float* comb = w;             w += BHz;
  float* gd = w;               w += BHz;
  float* gi_ = w;              w += BHz;
  float* go_ = w;              w += BHz;
  float* tgg = w;              w += BHz;
  float* dhgWx3 = w;           w += BHz;
  float* dhWd = w;             w += 6*BHz;
  float* pmean = w;            w += 8*BHz;
  float* pm = w;               w += (size_t)Bz*NCH*Hz;
  float* ps = w;               w += (size_t)Bz*NCH*Hz;
  float* pn = w;               w += (size_t)Bz*NCH*Hz;
  __bf16* h_bf  = (__bf16*)w;  w += NHz/2;
  __bf16* xe_bf = (__bf16*)w;  w += NHz/2;
  __bf16* Wp    = (__bf16*)w;  w += (6*32*256*32)/2;
  // total ~53.2M floats ~213 MB

  // one-time (per launch) conversions
  k_packW<<<768, 256, 0, stream>>>(Wx_g, Wh_g, Wi_g, Wp);
  k_toxe<<<(int)(NHz/4/256), 256, 0, stream>>>((const float4*)word, mask, (bf4_t*)xe_bf);
  k_init<<<(int)(NHz/4/256), 256, 0, stream>>>((const float4*)h0, (const float4*)c0, mask,
                                               (float4*)h_a, (float4*)c_a);
  k_meanp<<<dim3(Bz,8), 256, 0, stream>>>(h_a, pmean);
  k_comb8<<<Bz, 256, 0, stream>>>(pmean, dh_a);
  k_meanp<<<dim3(Bz,8), 256, 0, stream>>>(c_a, pmean);
  k_comb8<<<Bz, 256, 0, stream>>>(pmean, dc_a);

  float* hc=h_a; float* cc=c_a; float* hn=h_b; float* cn=c_b;
  float* dhc=dh_a; float* dcc=dc_a; float* dhn=dh_b; float* dcn=dc_b;

  for (int layer=0; layer<NLAYERS; ++layer){
    k_meanp<<<dim3(Bz,8), 256, 0, stream>>>(hc, pmean);
    k_comb8<<<Bz, 256, 0, stream>>>(pmean, comb);
    k_tobf16<<<(int)(NHz/4/256), 256, 0, stream>>>((const float4*)hc, (bf4_t*)h_bf);
    k_small<<<dim3(Bz,11), 256, 0, stream>>>(dhc, comb, sent, gWx, gWh, gWg, gb, Wd_g,
                                             ln_a, ln_b, gd, gi_, go_, tgg, dhgWx3, dhWd);
    k_gfsoft<<<Nz/16, 256, 0, stream>>>(hc, cc, dhgWx3, gWh + 3*Hz*Hz, gb + 3*Hz, mask,
                                        ln_a + 8*Hz, ln_b + 8*Hz, pm, ps, pn);
    k_soft_comb<<<Bz, 256, 0, stream>>>(pm, ps, pn, gd, gi_, go_, tgg, dcc, dcn, dhn);
    float* hout = (layer == NLAYERS-1) ? out : hn;
    k_fmfma<<<Nz/16, 256, 0, stream>>>(xe_bf, h_bf, Wp, word, cc, mask,
                                       dhWd, b_g, ln_a, ln_b, dcc, hout, cn);
    float* tmp;
    tmp=hc; hc=hn; hn=tmp;
    tmp=cc; cc=cn; cn=tmp;
    tmp=dhc; dhc=dhn; dhn=tmp;
    tmp=dcc; dcc=dcn; dcn=tmp;
  }
  (void)in_sizes; (void)n_in; (void)out_size; (void)ws_size;
}

// Round 4
// 2867.508 us; speedup vs baseline: 2.6070x; 1.1583x over previous
//
#include <hip/hip_runtime.h>
#include <cstddef>

#define Bz 32
#define Lz 1024
#define Hz 256
#define Nz (Bz*Lz)          // 32768
#define NHz ((size_t)Nz*Hz) // 8388608
#define BHz (Bz*Hz)         // 8192
#define EPSz 1e-3f
#define NLAYERS 4
#define NCH 64              // 16-row softmax chunks per batch
#define NTC 112             // tile-cols in pre (7 gates * 16)
#define CHROWS 8192         // rows per GEMM/epi chunk

typedef __bf16 bf8_t __attribute__((ext_vector_type(8)));
typedef __bf16 bf4_t __attribute__((ext_vector_type(4)));
typedef float  f4_t  __attribute__((ext_vector_type(4)));

__device__ inline float sigmoidf(float x){ return 1.f/(1.f+expf(-x)); }

__device__ inline float2 block_sum2(float a, float b, float* red){
  #pragma unroll
  for (int off=32; off; off>>=1){ a += __shfl_down(a,off,64); b += __shfl_down(b,off,64); }
  int w = threadIdx.x>>6;
  __syncthreads();
  if ((threadIdx.x&63)==0){ red[w]=a; red[4+w]=b; }
  __syncthreads();
  return make_float2(red[0]+red[1]+red[2]+red[3], red[4]+red[5]+red[6]+red[7]);
}

__device__ inline float ln_block(float v, const float* la, const float* lb, int t, float* red){
  float2 ss = block_sum2(v, v*v, red);
  float mean = ss.x*(1.f/Hz);
  float var  = (ss.y - (float)Hz*mean*mean)*(1.f/(Hz-1));
  float isd  = 1.f/(sqrtf(fmaxf(var,0.f))+EPSz);
  return la[t]*(v-mean)*isd + lb[t];
}

// ---- h = h0*mask, c = c0*mask ----
__global__ void k_init(const float4* __restrict__ h0, const float4* __restrict__ c0,
                       const float* __restrict__ mask, float4* __restrict__ h, float4* __restrict__ c){
  int e = blockIdx.x*blockDim.x + threadIdx.x;
  float m = mask[e>>6];
  float4 a = h0[e]; a.x*=m; a.y*=m; a.z*=m; a.w*=m; h[e]=a;
  float4 b = c0[e]; b.x*=m; b.y*=m; b.z*=m; b.w*=m; c[e]=b;
}

// ---- X cols 0..255 = word*mask (bf16), once per launch ----
__global__ void k_xe(const float* __restrict__ word, const float* __restrict__ mask,
                     __bf16* __restrict__ X){
  int tid = blockIdx.x*256 + threadIdx.x;      // Nz*32 threads
  int n = tid >> 5; int c8 = (tid & 31)*8;
  float m = mask[n];
  const float4* s = (const float4*)(word + (size_t)n*Hz + c8);
  float4 v0 = s[0], v1 = s[1];
  bf8_t o;
  o[0]=(__bf16)(v0.x*m); o[1]=(__bf16)(v0.y*m); o[2]=(__bf16)(v0.z*m); o[3]=(__bf16)(v0.w*m);
  o[4]=(__bf16)(v1.x*m); o[5]=(__bf16)(v1.y*m); o[6]=(__bf16)(v1.z*m); o[7]=(__bf16)(v1.w*m);
  *(bf8_t*)(X + (size_t)n*1024 + c8) = o;
}

// ---- X cols 256..1023 = [h(n-1) | h(n+1) | h(n)] (bf16), per layer ----
__global__ void k_xh(const float* __restrict__ h, __bf16* __restrict__ X){
  int tid = blockIdx.x*256 + threadIdx.x;      // Nz*128 threads
  int n = tid >> 7; int q = tid & 127;
  if (q < 32) return;
  int col = q*8;
  int seg = col >> 8, cl = col & 255;
  int l = n & 1023;
  float4 v0 = make_float4(0,0,0,0), v1 = v0;
  const float* src = nullptr;
  if (seg==1){ if (l!=0)    src = h + (size_t)(n-1)*Hz + cl; }
  else if (seg==2){ if (l!=1023) src = h + (size_t)(n+1)*Hz + cl; }
  else src = h + (size_t)n*Hz + cl;
  if (src){ v0 = *(const float4*)src; v1 = *(const float4*)(src+4); }
  bf8_t o;
  o[0]=(__bf16)v0.x; o[1]=(__bf16)v0.y; o[2]=(__bf16)v0.z; o[3]=(__bf16)v0.w;
  o[4]=(__bf16)v1.x; o[5]=(__bf16)v1.y; o[6]=(__bf16)v1.z; o[7]=(__bf16)v1.w;
  *(bf8_t*)(X + (size_t)n*1024 + col) = o;
}

// ---- pack 7-gate weights (1024 x 1792) into B-frag order:
//      Wp[((kb*1792 + col)*4 + p)*8 + j] = W[k=kb*32+p*8+j][col] ----
__global__ void k_packW7(const float* __restrict__ Wx, const float* __restrict__ Wh,
                         const float* __restrict__ Wi, const float* __restrict__ gWh3,
                         __bf16* __restrict__ Wp){
  int tid = blockIdx.x*256 + threadIdx.x;      // 229376 threads
  int p = tid & 3;
  int col = (tid>>2) & 2047; if (col >= 1792) return;
  int kb  = tid >> 13;
  int g = col >> 8, cg = col & 255;
  int seg = kb >> 3;
  int kl = (kb&7)*32 + p*8;
  const float* src = nullptr;
  if (g < 6){
    if (seg==0)      src = Wx + ((size_t)g*256 + kl)*256 + cg;
    else if (seg==1) src = Wh + ((size_t)g*512 + kl)*256 + cg;
    else if (seg==2) src = Wh + ((size_t)g*512 + 256 + kl)*256 + cg;
    else             src = Wi + ((size_t)g*256 + kl)*256 + cg;
  } else {
    if (seg==3)      src = gWh3 + (size_t)kl*256 + cg;
  }
  __bf16* dst = Wp + (((size_t)kb*1792 + col)*4 + p)*8;
  #pragma unroll
  for (int j=0;j<8;j++) dst[j] = src ? (__bf16)src[(size_t)j*256] : (__bf16)0.f;
}

// ---- mean over L, two-stage ----
__global__ void k_meanp(const float* __restrict__ x, float* __restrict__ part){
  int b = blockIdx.x, ch = blockIdx.y, t = threadIdx.x;
  const float* p = x + ((size_t)b*Lz + ch*128)*Hz + t;
  float s = 0.f;
  #pragma unroll 4
  for (int l=0;l<128;l++) s += p[(size_t)l*Hz];
  part[(b*8+ch)*Hz + t] = s;
}
__global__ void k_comb8(const float* __restrict__ part, float* __restrict__ o){
  int b = blockIdx.x, t = threadIdx.x;
  float s = 0.f;
  #pragma unroll
  for (int ch=0;ch<8;ch++) s += part[(b*8+ch)*Hz + t];
  o[b*Hz+t] = s*(1.f/Lz);
}

// ---- sentence-level gates + broadcast matvecs.  grid (B, 11) ----
__global__ __launch_bounds__(256) void k_small(
    const float* __restrict__ dh, const float* __restrict__ comb, const float* __restrict__ sent,
    const float* __restrict__ gWx, const float* __restrict__ gWh, const float* __restrict__ gWg,
    const float* __restrict__ gb, const float* __restrict__ Wd_g,
    const float* __restrict__ ln_a, const float* __restrict__ ln_b,
    float* __restrict__ gd, float* __restrict__ gi, float* __restrict__ go,
    float* __restrict__ tgg, float* __restrict__ dhWd7){
  int b = blockIdx.x, which = blockIdx.y, t = threadIdx.x;
  __shared__ float sdh[Hz], sse[Hz], sco[Hz];
  __shared__ float red[8];
  sdh[t]=dh[b*Hz+t]; sse[t]=sent[b*Hz+t]; sco[t]=comb[b*Hz+t];
  __syncthreads();
  float acc=0.f;
  if (which < 3){
    const float* W0 = gWx + which*Hz*Hz;
    const float* W1 = gWg + which*Hz*Hz;
    const float* W2 = gWh + which*Hz*Hz;
    for (int k=0;k<Hz;k++) acc += sdh[k]*W0[k*Hz+t] + sse[k]*W1[k*Hz+t] + sco[k]*W2[k*Hz+t];
    if (which==0){
      float r = ln_block(acc + gb[0*Hz+t], ln_a+6*Hz, ln_b+6*Hz, t, red);
      gd[b*Hz+t] = sigmoidf(r);
    } else if (which==1){
      float r = ln_block(acc, ln_a+9*Hz, ln_b+9*Hz, t, red);
      gi[b*Hz+t] = sigmoidf(r + gb[1*Hz+t]);
    } else {
      float r = ln_block(acc + gb[2*Hz+t], ln_a+7*Hz, ln_b+7*Hz, t, red);
      go[b*Hz+t] = sigmoidf(r);
    }
  } else if (which == 3){
    const float* W = gWg + 3*Hz*Hz;
    for (int k=0;k<Hz;k++) acc += sse[k]*W[k*Hz+t];
    float r = ln_block(acc, ln_a+10*Hz, ln_b+10*Hz, t, red);
    tgg[b*Hz+t] = tanhf(r);
  } else if (which == 4){
    const float* W = gWx + 3*Hz*Hz;          // dh @ gWx[3]  -> slot 6
    for (int k=0;k<Hz;k++) acc += sdh[k]*W[k*Hz+t];
    dhWd7[(6*Bz + b)*Hz + t] = acc;
  } else {
    int g = which-5;
    const float* W = Wd_g + g*Hz*Hz;
    for (int k=0;k<Hz;k++) acc += sdh[k]*W[k*Hz+t];
    dhWd7[(g*Bz + b)*Hz + t] = acc;
  }
}

// ---- GEMM: X(rows x 1024) @ Wp(1024 x 1792) -> pre (bf16, frag-tile order).
//      128x128 tile/block, 4 waves, 16 MFMA tiles/wave, no LDS, no barriers. ----
__global__ __launch_bounds__(256,4) void k_gemm(
    const __bf16* __restrict__ X, const __bf16* __restrict__ Wp,
    __bf16* __restrict__ pre, int n_base){
  int t = threadIdx.x;
  int w = t>>6, lane = t&63;
  int m16 = lane&15, p = lane>>4;
  int bx = blockIdx.x, by = blockIdx.y;
  int row0 = n_base + bx*128 + (w&1)*64;
  int colq = by*128 + (w>>1)*64;
  int kb0 = (by >= 12) ? 24 : 0;               // gate-6 cols: only seg 3

  f4_t acc[4][4];
  #pragma unroll
  for (int i=0;i<4;i++)
    #pragma unroll
    for (int j=0;j<4;j++) acc[i][j] = (f4_t){0.f,0.f,0.f,0.f};

  const __bf16* Xb = X + (size_t)(row0 + m16)*1024 + p*8;
  const __bf16* Wb = Wp + ((size_t)(colq + m16)*4 + p)*8;

  for (int kb=kb0; kb<32; ++kb){
    bf8_t a[4], bb[4];
    size_t ko = (size_t)kb*32;
    size_t wo = (size_t)kb*57344;              // 1792*4*8
    #pragma unroll
    for (int tr=0;tr<4;tr++) a[tr]  = *(const bf8_t*)(Xb + (size_t)tr*16384 + ko);
    #pragma unroll
    for (int tc=0;tc<4;tc++) bb[tc] = *(const bf8_t*)(Wb + wo + tc*512);
    #pragma unroll
    for (int tr=0;tr<4;tr++)
      #pragma unroll
      for (int tc=0;tc<4;tc++)
        acc[tr][tc] = __builtin_amdgcn_mfma_f32_16x16x32_bf16(a[tr], bb[tc], acc[tr][tc], 0, 0, 0);
  }

  int trg0 = (bx*128 + (w&1)*64) >> 4;         // chunk-local tile row
  int tcg0 = colq >> 4;
  #pragma unroll
  for (int tr=0;tr<4;tr++){
    #pragma unroll
    for (int tc=0;tc<4;tc++){
      size_t tile = (size_t)(trg0+tr)*NTC + (tcg0+tc);
      bf4_t o;
      o[0]=(__bf16)acc[tr][tc][0]; o[1]=(__bf16)acc[tr][tc][1];
      o[2]=(__bf16)acc[tr][tc][2]; o[3]=(__bf16)acc[tr][tc][3];
      *(bf4_t*)(pre + tile*256 + lane*4) = o;
    }
  }
}

// ---- epilogue: read pre (frag layout), +dhWd*mask+bias, LN x7, sigmoid,
//      gate6 -> msm + online-softmax partials; gates0-5 -> 5-softmax cell update.
//      hn/cn staged through LDS for coalesced stores. 16 rows/block. ----
__global__ __launch_bounds__(256) void k_epi(
    const __bf16* __restrict__ pre, const float* __restrict__ word, const float* __restrict__ c,
    const float* __restrict__ mask, const float* __restrict__ dhWd7, const float* __restrict__ b_g,
    const float* __restrict__ gb3, const float* __restrict__ ln_a, const float* __restrict__ ln_b,
    const float* __restrict__ dc,
    float* __restrict__ hn, float* __restrict__ cn,
    float* __restrict__ pm, float* __restrict__ ps, float* __restrict__ pn, int n_base){
  __shared__ float smask[16];
  __shared__ float sred_s[4][7][16];
  __shared__ float sred_q[4][7][16];
  __shared__ float hsh[16*260];
  int t = threadIdx.x;
  int n0 = n_base + blockIdx.x*16;
  int b = n0 >> 10;
  if (t < 16) smask[t] = mask[n0 + t];
  __syncthreads();
  int w = t>>6, lane = t&63, m16 = lane&15, p = lane>>4;
  size_t trk = blockIdx.x;

  float acc[7][4][4];

  // load + bias + LN row-stat partials
  #pragma unroll 1
  for (int g=0; g<7; ++g){
    float s_r[4] = {0.f,0.f,0.f,0.f};
    float q_r[4] = {0.f,0.f,0.f,0.f};
    #pragma unroll
    for (int tc=0; tc<4; ++tc){
      int col = (w + tc*4)*16 + m16;
      size_t tile = trk*NTC + g*16 + w + tc*4;
      bf4_t pv = *(const bf4_t*)(pre + tile*256 + lane*4);
      float wd = dhWd7[(g*Bz + b)*Hz + col];
      float bg = (g<6) ? b_g[g*Hz + col] : gb3[col];
      #pragma unroll
      for (int reg=0; reg<4; ++reg){
        float x = (float)pv[reg] + smask[p*4+reg]*wd + bg;
        acc[g][tc][reg] = x;
        s_r[reg] += x; q_r[reg] += x*x;
      }
    }
    #pragma unroll
    for (int off=1; off<16; off<<=1){
      #pragma unroll
      for (int reg=0; reg<4; ++reg){
        s_r[reg] += __shfl_xor(s_r[reg], off, 64);
        q_r[reg] += __shfl_xor(q_r[reg], off, 64);
      }
    }
    if (m16==0){
      #pragma unroll
      for (int reg=0; reg<4; ++reg){
        sred_s[w][g][p*4+reg] = s_r[reg];
        sred_q[w][g][p*4+reg] = q_r[reg];
      }
    }
  }
  __syncthreads();

  // LN + sigmoid
  #pragma unroll 1
  for (int g=0; g<7; ++g){
    float mean_r[4], isd_r[4];
    #pragma unroll
    for (int reg=0; reg<4; ++reg){
      int row = p*4+reg;
      float ss = sred_s[0][g][row]+sred_s[1][g][row]+sred_s[2][g][row]+sred_s[3][g][row];
      float qq = sred_q[0][g][row]+sred_q[1][g][row]+sred_q[2][g][row]+sred_q[3][g][row];
      float mean = ss*(1.f/Hz);
      float var  = (qq - (float)Hz*mean*mean)*(1.f/(Hz-1));
      mean_r[reg] = mean;
      isd_r[reg]  = 1.f/(sqrtf(fmaxf(var,0.f))+EPSz);
    }
    int lnr = (g<6) ? g : 8;
    #pragma unroll
    for (int tc=0; tc<4; ++tc){
      int col = (w + tc*4)*16 + m16;
      float la = ln_a[lnr*Hz+col], lb = ln_b[lnr*Hz+col];
      #pragma unroll
      for (int reg=0; reg<4; ++reg){
        acc[g][tc][reg] = sigmoidf(la*(acc[g][tc][reg]-mean_r[reg])*isd_r[reg] + lb);
      }
    }
  }

  // current-cell loads (reused by gate-6 partials and cell update)
  float cvv[4][4];
  #pragma unroll
  for (int tc=0; tc<4; ++tc){
    int col = (w + tc*4)*16 + m16;
    #pragma unroll
    for (int reg=0; reg<4; ++reg)
      cvv[tc][reg] = c[(size_t)(n0 + p*4 + reg)*Hz + col];
  }

  // gate-6: gf = sig + msm; online softmax partials over this block's 16 rows per column
  int ch = (n0 >> 4) & (NCH-1);
  #pragma unroll 1
  for (int tc=0; tc<4; ++tc){
    int col = (w + tc*4)*16 + m16;
    float mm = -1e30f;
    float gfv[4];
    #pragma unroll
    for (int reg=0; reg<4; ++reg){
      float gv = acc[6][tc][reg] + (smask[p*4+reg]*1e25f - 1e25f);
      gfv[reg] = gv;
      mm = fmaxf(mm, gv);
    }
    float ss=0.f, nn=0.f;
    #pragma unroll
    for (int reg=0; reg<4; ++reg){
      float e = expf(gfv[reg]-mm);
      ss += e; nn += e*cvv[tc][reg];
    }
    #pragma unroll
    for (int off=16; off<64; off<<=1){
      float mo = __shfl_xor(mm, off, 64);
      float so = __shfl_xor(ss, off, 64);
      float no = __shfl_xor(nn, off, 64);
      float mN = fmaxf(mm, mo);
      float ea = expf(mm-mN), eb = expf(mo-mN);
      ss = ss*ea + so*eb; nn = nn*ea + no*eb; mm = mN;
    }
    if (p==0){
      int idx = (b*NCH + ch)*Hz + col;
      pm[idx]=mm; ps[idx]=ss; pn[idx]=nn;
    }
  }

  // 5-softmax + cell update; stage hn in LDS, keep cn in acc[0]
  #pragma unroll 1
  for (int tc=0; tc<4; ++tc){
    int col = (w + tc*4)*16 + m16;
    float tdc = dc[b*Hz + col];
    #pragma unroll
    for (int reg=0; reg<4; ++reg){
      int n2 = n0 + p*4 + reg;
      int l2 = n2 & 1023;
      float msk = smask[p*4+reg];
      float g0=acc[0][tc][reg], g1=acc[1][tc][reg], g2=acc[2][tc][reg],
            g3=acc[3][tc][reg], g4=acc[4][tc][reg];
      float m5 = fmaxf(fmaxf(fmaxf(g0,g1),fmaxf(g2,g3)),g4);
      float e0=expf(g0-m5), e1=expf(g1-m5), e2=expf(g2-m5), e3=expf(g3-m5), e4=expf(g4-m5);
      float inv = 1.f/(e0+e1+e2+e3+e4);
      float cb = (l2==0)    ? 0.f : c[(size_t)(n2-1)*Hz + col];
      float ca = (l2==1023) ? 0.f : c[(size_t)(n2+1)*Hz + col];
      float em = word[(size_t)n2*Hz + col]*msk;
      float td = tdc*msk;
      float cnew = (cb*e0 + ca*e1 + em*e2 + td*e3 + cvv[tc][reg]*e4)*inv;
      float hv = acc[5][tc][reg]*tanhf(cnew);
      hsh[(p*4+reg)*260 + col] = hv*msk;
      acc[0][tc][reg] = cnew*msk;
    }
  }
  __syncthreads();
  {
    int row = t>>4, c16 = (t&15)*16;
    const float* src = hsh + row*260 + c16;
    float4* dst = (float4*)(hn + (size_t)(n0+row)*Hz + c16);
    float4 v0 = *(const float4*)(src+0), v1 = *(const float4*)(src+4);
    float4 v2 = *(const float4*)(src+8), v3 = *(const float4*)(src+12);
    dst[0]=v0; dst[1]=v1; dst[2]=v2; dst[3]=v3;
  }
  __syncthreads();
  #pragma unroll
  for (int tc=0; tc<4; ++tc){
    int col = (w + tc*4)*16 + m16;
    #pragma unroll
    for (int reg=0; reg<4; ++reg)
      hsh[(p*4+reg)*260 + col] = acc[0][tc][reg];
  }
  __syncthreads();
  {
    int row = t>>4, c16 = (t&15)*16;
    const float* src = hsh + row*260 + c16;
    float4* dst = (float4*)(cn + (size_t)(n0+row)*Hz + c16);
    float4 v0 = *(const float4*)(src+0), v1 = *(const float4*)(src+4);
    float4 v2 = *(const float4*)(src+8), v3 = *(const float4*)(src+12);
    dst[0]=v0; dst[1]=v1; dst[2]=v2; dst[3]=v3;
  }
}

// ---- combine partials + gd/gi slots -> dc_new, dh_new ----
__global__ void k_soft_comb(const float* __restrict__ pm, const float* __restrict__ ps,
    const float* __restrict__ pn,
    const float* __restrict__ gd, const float* __restrict__ gi, const float* __restrict__ go,
    const float* __restrict__ tgg, const float* __restrict__ dc,
    float* __restrict__ dc_new, float* __restrict__ dh_new){
  int b = blockIdx.x, t = threadIdx.x;
  float vgd = gd[b*Hz+t], vgi = gi[b*Hz+t];
  float m = fmaxf(vgd, vgi);
  for (int ch=0; ch<NCH; ch++) m = fmaxf(m, pm[(b*NCH+ch)*Hz + t]);
  float ed = expf(vgd - m), ei = expf(vgi - m);
  float s  = ed + ei;
  float num = ed*dc[b*Hz+t] + ei*tgg[b*Hz+t];
  for (int ch=0; ch<NCH; ch++){
    int idx = (b*NCH+ch)*Hz + t;
    float e = expf(pm[idx] - m);
    s   += ps[idx]*e;
    num += pn[idx]*e;
  }
  float dcn = num/s;
  dc_new[b*Hz+t] = dcn;
  dh_new[b*Hz+t] = go[b*Hz+t]*tanhf(dcn);
}

extern "C" void kernel_launch(void* const* d_in, const int* in_sizes, int n_in,
                              void* d_out, int out_size, void* d_ws, size_t ws_size,
                              hipStream_t stream) {
  const float* word  = (const float*)d_in[0];
  const float* sent  = (const float*)d_in[1];
  const float* mask  = (const float*)d_in[2];
  const float* h0    = (const float*)d_in[3];
  const float* c0    = (const float*)d_in[4];
  const float* Wx_g  = (const float*)d_in[5];
  const float* Wh_g  = (const float*)d_in[6];
  const float* Wi_g  = (const float*)d_in[7];
  const float* Wd_g  = (const float*)d_in[8];
  const float* b_g   = (const float*)d_in[9];
  const float* gWx   = (const float*)d_in[10];
  const float* gWh   = (const float*)d_in[11];
  const float* gWg   = (const float*)d_in[12];
  const float* gb    = (const float*)d_in[13];
  const float* ln_a  = (const float*)d_in[14];
  const float* ln_b  = (const float*)d_in[15];
  float* out = (float*)d_out;

  float* w = (float*)d_ws;
  float* h_   = w;             w += NHz;            // single h buffer (in-place update)
  float* c_a  = w;             w += NHz;
  float* c_b  = w;             w += NHz;
  float* dh_a = w;             w += BHz;
  float* dh_b = w;             w += BHz;
  float* dc_a = w;             w += BHz;
  float* dc_b = w;             w += BHz;
  float* comb = w;             w += BHz;
  float* gd   = w;             w += BHz;
  float* gi_  = w;             w += BHz;
  float* go_  = w;             w += BHz;
  float* tgg  = w;             w += BHz;
  float* dhWd7 = w;            w += 7*BHz;
  float* pmean = w;            w += 8*BHz;
  float* pm = w;               w += (size_t)Bz*NCH*Hz;
  float* ps = w;               w += (size_t)Bz*NCH*Hz;
  float* pn = w;               w += (size_t)Bz*NCH*Hz;
  __bf16* X   = (__bf16*)w;    w += (size_t)Nz*1024/2;
  __bf16* Wp  = (__bf16*)w;    w += (size_t)32*1792*32/2;
  __bf16* pre = (__bf16*)w;    w += (size_t)(CHROWS/16)*NTC*256/2;
  // ~207 MB total

  // setup
  k_packW7<<<1024, 256, 0, stream>>>(Wx_g, Wh_g, Wi_g, gWh + 3*Hz*Hz, Wp);
  k_xe<<<4096, 256, 0, stream>>>(word, mask, X);
  k_init<<<(int)(NHz/4/256), 256, 0, stream>>>((const float4*)h0, (const float4*)c0, mask,
                                               (float4*)h_, (float4*)c_a);
  k_meanp<<<dim3(Bz,8), 256, 0, stream>>>(h_, pmean);
  k_comb8<<<Bz, 256, 0, stream>>>(pmean, dh_a);
  k_meanp<<<dim3(Bz,8), 256, 0, stream>>>(c_a, pmean);
  k_comb8<<<Bz, 256, 0, stream>>>(pmean, dc_a);

  float* cc=c_a; float* cn=c_b;
  float* dhc=dh_a; float* dcc=dc_a; float* dhn=dh_b; float* dcn=dc_b;

  for (int layer=0; layer<NLAYERS; ++layer){
    k_meanp<<<dim3(Bz,8), 256, 0, stream>>>(h_, pmean);
    k_comb8<<<Bz, 256, 0, stream>>>(pmean, comb);
    k_small<<<dim3(Bz,11), 256, 0, stream>>>(dhc, comb, sent, gWx, gWh, gWg, gb, Wd_g,
                                             ln_a, ln_b, gd, gi_, go_, tgg, dhWd7);
    k_xh<<<16384, 256, 0, stream>>>(h_, X);
    float* hout = (layer == NLAYERS-1) ? out : h_;
    for (int chunk=0; chunk<Nz/CHROWS; ++chunk){
      int n_base = chunk*CHROWS;
      k_gemm<<<dim3(CHROWS/128, 14), 256, 0, stream>>>(X, Wp, pre, n_base);
      k_epi<<<CHROWS/16, 256, 0, stream>>>(pre, word, cc, mask, dhWd7, b_g, gb + 3*Hz,
                                           ln_a, ln_b, dcc, hout, cn, pm, ps, pn, n_base);
    }
    k_soft_comb<<<Bz, 256, 0, stream>>>(pm, ps, pn, gd, gi_, go_, tgg, dcc, dcn, dhn);
    float* tmp;
    tmp=cc; cc=cn; cn=tmp;
    tmp=dhc; dhc=dhn; dhn=tmp;
    tmp=dcc; dcc=dcn; dcn=tmp;
  }
  (void)in_sizes; (void)n_in; (void)out_size; (void)ws_size;
}

// Round 6
// 2771.354 us; speedup vs baseline: 2.6975x; 1.0347x over previous
//
#include <hip/hip_runtime.h>
#include <cstddef>

#define Bz 32
#define Lz 1024
#define Hz 256
#define Nz (Bz*Lz)          // 32768
#define NHz ((size_t)Nz*Hz) // 8388608
#define BHz (Bz*Hz)         // 8192
#define EPSz 1e-3f
#define NLAYERS 4
#define NCH 64              // 16-row softmax chunks per batch
#define NTC 112             // tile-cols in pre (7 gates * 16)
#define CHR 16384           // rows per GEMM/epi chunk

typedef __bf16 bf8_t __attribute__((ext_vector_type(8)));
typedef __bf16 bf4_t __attribute__((ext_vector_type(4)));
typedef float  f4_t  __attribute__((ext_vector_type(4)));

__device__ inline float sigmoidf(float x){ return 1.f/(1.f+expf(-x)); }

__device__ inline float2 block_sum2(float a, float b, float* red){
  #pragma unroll
  for (int off=32; off; off>>=1){ a += __shfl_down(a,off,64); b += __shfl_down(b,off,64); }
  int w = threadIdx.x>>6;
  __syncthreads();
  if ((threadIdx.x&63)==0){ red[w]=a; red[4+w]=b; }
  __syncthreads();
  return make_float2(red[0]+red[1]+red[2]+red[3], red[4]+red[5]+red[6]+red[7]);
}

__device__ inline float ln_block(float v, const float* la, const float* lb, int t, float* red){
  float2 ss = block_sum2(v, v*v, red);
  float mean = ss.x*(1.f/Hz);
  float var  = (ss.y - (float)Hz*mean*mean)*(1.f/(Hz-1));
  float isd  = 1.f/(sqrtf(fmaxf(var,0.f))+EPSz);
  return la[t]*(v-mean)*isd + lb[t];
}

// ---- init: xe = word*mask, h = h0*mask, c = c0*mask (all bf16) ----
__global__ void k_initb(const float* __restrict__ word, const float* __restrict__ h0,
                        const float* __restrict__ c0, const float* __restrict__ mask,
                        __bf16* __restrict__ xe, __bf16* __restrict__ h, __bf16* __restrict__ c){
  int tid = blockIdx.x*256 + threadIdx.x;      // Nz*32 threads
  int n = tid >> 5; int c8 = (tid & 31)*8;
  float m = mask[n];
  size_t off = (size_t)n*Hz + c8;
  const float4* wv = (const float4*)(word + off);
  float4 w0 = wv[0], w1 = wv[1];
  bf8_t o;
  o[0]=(__bf16)(w0.x*m); o[1]=(__bf16)(w0.y*m); o[2]=(__bf16)(w0.z*m); o[3]=(__bf16)(w0.w*m);
  o[4]=(__bf16)(w1.x*m); o[5]=(__bf16)(w1.y*m); o[6]=(__bf16)(w1.z*m); o[7]=(__bf16)(w1.w*m);
  *(bf8_t*)(xe + off) = o;
  const float4* hv = (const float4*)(h0 + off);
  float4 a0 = hv[0], a1 = hv[1];
  o[0]=(__bf16)(a0.x*m); o[1]=(__bf16)(a0.y*m); o[2]=(__bf16)(a0.z*m); o[3]=(__bf16)(a0.w*m);
  o[4]=(__bf16)(a1.x*m); o[5]=(__bf16)(a1.y*m); o[6]=(__bf16)(a1.z*m); o[7]=(__bf16)(a1.w*m);
  *(bf8_t*)(h + off) = o;
  const float4* cv = (const float4*)(c0 + off);
  float4 b0 = cv[0], b1 = cv[1];
  o[0]=(__bf16)(b0.x*m); o[1]=(__bf16)(b0.y*m); o[2]=(__bf16)(b0.z*m); o[3]=(__bf16)(b0.w*m);
  o[4]=(__bf16)(b1.x*m); o[5]=(__bf16)(b1.y*m); o[6]=(__bf16)(b1.z*m); o[7]=(__bf16)(b1.w*m);
  *(bf8_t*)(c + off) = o;
}

// ---- pack 7-gate weights (1024 x 1792) into B-frag order ----
__global__ void k_packW7(const float* __restrict__ Wx, const float* __restrict__ Wh,
                         const float* __restrict__ Wi, const float* __restrict__ gWh3,
                         __bf16* __restrict__ Wp){
  int tid = blockIdx.x*256 + threadIdx.x;
  int p = tid & 3;
  int col = (tid>>2) & 2047; if (col >= 1792) return;
  int kb  = tid >> 13;
  int g = col >> 8, cg = col & 255;
  int seg = kb >> 3;
  int kl = (kb&7)*32 + p*8;
  const float* src = nullptr;
  if (g < 6){
    if (seg==0)      src = Wx + ((size_t)g*256 + kl)*256 + cg;
    else if (seg==1) src = Wh + ((size_t)g*512 + kl)*256 + cg;
    else if (seg==2) src = Wh + ((size_t)g*512 + 256 + kl)*256 + cg;
    else             src = Wi + ((size_t)g*256 + kl)*256 + cg;
  } else {
    if (seg==3)      src = gWh3 + (size_t)kl*256 + cg;
  }
  __bf16* dst = Wp + (((size_t)kb*1792 + col)*4 + p)*8;
  #pragma unroll
  for (int j=0;j<8;j++) dst[j] = src ? (__bf16)src[(size_t)j*256] : (__bf16)0.f;
}

// ---- mean over L of a bf16 tensor, two-stage ----
__global__ void k_meanpb(const __bf16* __restrict__ x, float* __restrict__ part){
  int b = blockIdx.x, ch = blockIdx.y, t = threadIdx.x;
  const __bf16* p = x + ((size_t)b*Lz + ch*128)*Hz + t;
  float s = 0.f;
  #pragma unroll 4
  for (int l=0;l<128;l++) s += (float)p[(size_t)l*Hz];
  part[(b*8+ch)*Hz + t] = s;
}
__global__ void k_comb8(const float* __restrict__ part, float* __restrict__ o){
  int b = blockIdx.x, t = threadIdx.x;
  float s = 0.f;
  #pragma unroll
  for (int ch=0;ch<8;ch++) s += part[(b*8+ch)*Hz + t];
  o[b*Hz+t] = s*(1.f/Lz);
}

// ---- sentence-level gates + broadcast matvecs.  grid (B, 11) ----
__global__ __launch_bounds__(256) void k_small(
    const float* __restrict__ dh, const float* __restrict__ comb, const float* __restrict__ sent,
    const float* __restrict__ gWx, const float* __restrict__ gWh, const float* __restrict__ gWg,
    const float* __restrict__ gb, const float* __restrict__ Wd_g,
    const float* __restrict__ ln_a, const float* __restrict__ ln_b,
    float* __restrict__ gd, float* __restrict__ gi, float* __restrict__ go,
    float* __restrict__ tgg, float* __restrict__ dhWd7){
  int b = blockIdx.x, which = blockIdx.y, t = threadIdx.x;
  __shared__ float sdh[Hz], sse[Hz], sco[Hz];
  __shared__ float red[8];
  sdh[t]=dh[b*Hz+t]; sse[t]=sent[b*Hz+t]; sco[t]=comb[b*Hz+t];
  __syncthreads();
  float acc=0.f;
  if (which < 3){
    const float* W0 = gWx + which*Hz*Hz;
    const float* W1 = gWg + which*Hz*Hz;
    const float* W2 = gWh + which*Hz*Hz;
    for (int k=0;k<Hz;k++) acc += sdh[k]*W0[k*Hz+t] + sse[k]*W1[k*Hz+t] + sco[k]*W2[k*Hz+t];
    if (which==0){
      float r = ln_block(acc + gb[0*Hz+t], ln_a+6*Hz, ln_b+6*Hz, t, red);
      gd[b*Hz+t] = sigmoidf(r);
    } else if (which==1){
      float r = ln_block(acc, ln_a+9*Hz, ln_b+9*Hz, t, red);
      gi[b*Hz+t] = sigmoidf(r + gb[1*Hz+t]);
    } else {
      float r = ln_block(acc + gb[2*Hz+t], ln_a+7*Hz, ln_b+7*Hz, t, red);
      go[b*Hz+t] = sigmoidf(r);
    }
  } else if (which == 3){
    const float* W = gWg + 3*Hz*Hz;
    for (int k=0;k<Hz;k++) acc += sse[k]*W[k*Hz+t];
    float r = ln_block(acc, ln_a+10*Hz, ln_b+10*Hz, t, red);
    tgg[b*Hz+t] = tanhf(r);
  } else if (which == 4){
    const float* W = gWx + 3*Hz*Hz;          // dh @ gWx[3] -> slot 6
    for (int k=0;k<Hz;k++) acc += sdh[k]*W[k*Hz+t];
    dhWd7[(6*Bz + b)*Hz + t] = acc;
  } else {
    int g = which-5;
    const float* W = Wd_g + g*Hz*Hz;
    for (int k=0;k<Hz;k++) acc += sdh[k]*W[k*Hz+t];
    dhWd7[(g*Bz + b)*Hz + t] = acc;
  }
}

// ---- GEMM: [xe | h(n-1) | h(n+1) | h(n)](rows x 1024) @ Wp(1024 x 1792) -> pre ----
__global__ __launch_bounds__(256,4) void k_gemm(
    const __bf16* __restrict__ xe, const __bf16* __restrict__ h,
    const __bf16* __restrict__ Wp, __bf16* __restrict__ pre, int n_base){
  int t = threadIdx.x;
  int w = t>>6, lane = t&63;
  int m16 = lane&15, p = lane>>4;
  int bx = blockIdx.x, by = blockIdx.y;
  int row0 = n_base + bx*128 + (w&1)*64;
  int colq = by*128 + (w>>1)*64;

  f4_t acc[4][4];
  #pragma unroll
  for (int i=0;i<4;i++)
    #pragma unroll
    for (int j=0;j<4;j++) acc[i][j] = (f4_t){0.f,0.f,0.f,0.f};

  bf8_t az;
  #pragma unroll
  for (int j=0;j<8;j++) az[j] = (__bf16)0.f;

  int r[4], l[4];
  #pragma unroll
  for (int tr=0;tr<4;tr++){ r[tr] = row0 + tr*16 + m16; l[tr] = r[tr]&1023; }
  const __bf16* Wb = Wp + ((size_t)(colq + m16)*4 + p)*8;
  int koff = p*8;

  int seg_s = (by >= 12) ? 3 : 0;              // gate-6 cols: only seg 3
  #pragma unroll 1
  for (int seg=seg_s; seg<4; ++seg){
    const __bf16* ab[4];
    bool val[4];
    #pragma unroll
    for (int tr=0;tr<4;tr++){
      if (seg==0){      ab[tr] = xe + (size_t)r[tr]*Hz; val[tr]=true; }
      else if (seg==1){ ab[tr] = h + (size_t)(r[tr]-1)*Hz; val[tr] = (l[tr]!=0); }
      else if (seg==2){ ab[tr] = h + (size_t)(r[tr]+1)*Hz; val[tr] = (l[tr]!=1023); }
      else {            ab[tr] = h + (size_t)r[tr]*Hz; val[tr]=true; }
    }
    #pragma unroll 2
    for (int kq=0; kq<8; ++kq){
      int kb = seg*8 + kq;
      bf8_t a[4], bb[4];
      #pragma unroll
      for (int tr=0;tr<4;tr++)
        a[tr] = val[tr] ? *(const bf8_t*)(ab[tr] + kq*32 + koff) : az;
      size_t wo = (size_t)kb*57344;            // 1792*4*8
      #pragma unroll
      for (int tc=0;tc<4;tc++) bb[tc] = *(const bf8_t*)(Wb + wo + tc*512);
      #pragma unroll
      for (int tr=0;tr<4;tr++)
        #pragma unroll
        for (int tc=0;tc<4;tc++)
          acc[tr][tc] = __builtin_amdgcn_mfma_f32_16x16x32_bf16(a[tr], bb[tc], acc[tr][tc], 0, 0, 0);
    }
  }

  int trg0 = (bx*128 + (w&1)*64) >> 4;         // chunk-local tile row
  int tcg0 = colq >> 4;
  #pragma unroll
  for (int tr=0;tr<4;tr++){
    #pragma unroll
    for (int tc=0;tc<4;tc++){
      size_t tile = (size_t)(trg0+tr)*NTC + (tcg0+tc);
      bf4_t o;
      o[0]=(__bf16)acc[tr][tc][0]; o[1]=(__bf16)acc[tr][tc][1];
      o[2]=(__bf16)acc[tr][tc][2]; o[3]=(__bf16)acc[tr][tc][3];
      *(bf4_t*)(pre + tile*256 + lane*4) = o;
    }
  }
}

// ---- epilogue (1024 threads): wave w16 owns cols [w16*16, w16*16+16) across all 7 gates ----
__global__ __launch_bounds__(1024) void k_epi(
    const __bf16* __restrict__ pre, const __bf16* __restrict__ xe,
    const __bf16* __restrict__ cc, const float* __restrict__ mask,
    const float* __restrict__ dhWd7, const float* __restrict__ b_g,
    const float* __restrict__ gb3, const float* __restrict__ ln_a, const float* __restrict__ ln_b,
    const float* __restrict__ dc,
    float* __restrict__ outf, __bf16* __restrict__ hn, __bf16* __restrict__ cn,
    float* __restrict__ pm, float* __restrict__ ps, float* __restrict__ pn,
    int n_base, int last){
  __shared__ float smask[16];
  __shared__ float sred_s[16][7][16];
  __shared__ float sred_q[16][7][16];
  __shared__ float hsh[16*260];
  int t = threadIdx.x;
  int n0 = n_base + blockIdx.x*16;
  int b = n0 >> 10;
  if (t < 16) smask[t] = mask[n0 + t];
  __syncthreads();
  int w16 = t>>6, lane = t&63, m16 = lane&15, p = lane>>4;
  int col = w16*16 + m16;
  size_t trk = blockIdx.x;

  float acc[7][4];
  #pragma unroll 1
  for (int g=0; g<7; ++g){
    size_t tile = trk*NTC + g*16 + w16;
    bf4_t pv = *(const bf4_t*)(pre + tile*256 + lane*4);
    float wd = dhWd7[(g*Bz + b)*Hz + col];
    float bg = (g<6) ? b_g[g*Hz + col] : gb3[col];
    float s_r[4], q_r[4];
    #pragma unroll
    for (int reg=0; reg<4; ++reg){
      float x = (float)pv[reg] + smask[p*4+reg]*wd + bg;
      acc[g][reg] = x;
      s_r[reg] = x; q_r[reg] = x*x;
    }
    #pragma unroll
    for (int off=1; off<16; off<<=1){
      #pragma unroll
      for (int reg=0; reg<4; ++reg){
        s_r[reg] += __shfl_xor(s_r[reg], off, 64);
        q_r[reg] += __shfl_xor(q_r[reg], off, 64);
      }
    }
    if (m16==0){
      #pragma unroll
      for (int reg=0; reg<4; ++reg){
        sred_s[w16][g][p*4+reg] = s_r[reg];
        sred_q[w16][g][p*4+reg] = q_r[reg];
      }
    }
  }
  __syncthreads();

  #pragma unroll 1
  for (int g=0; g<7; ++g){
    int lnr = (g<6) ? g : 8;
    float la = ln_a[lnr*Hz+col], lb = ln_b[lnr*Hz+col];
    #pragma unroll
    for (int reg=0; reg<4; ++reg){
      int row = p*4+reg;
      float ss=0.f, qq=0.f;
      #pragma unroll
      for (int ww=0; ww<16; ++ww){ ss += sred_s[ww][g][row]; qq += sred_q[ww][g][row]; }
      float mean = ss*(1.f/Hz);
      float var  = (qq - (float)Hz*mean*mean)*(1.f/(Hz-1));
      float isd  = 1.f/(sqrtf(fmaxf(var,0.f))+EPSz);
      acc[g][reg] = sigmoidf(la*(acc[g][reg]-mean)*isd + lb);
    }
  }

  float cvv[4];
  #pragma unroll
  for (int reg=0; reg<4; ++reg)
    cvv[reg] = (float)cc[(size_t)(n0 + p*4 + reg)*Hz + col];

  // gate-6: msm + online-softmax partials over the block's 16 rows per column
  {
    float mm = -1e30f, gfv[4];
    #pragma unroll
    for (int reg=0; reg<4; ++reg){
      float gv = acc[6][reg] + (smask[p*4+reg]*1e25f - 1e25f);
      gfv[reg] = gv;
      mm = fmaxf(mm, gv);
    }
    float ss=0.f, nn=0.f;
    #pragma unroll
    for (int reg=0; reg<4; ++reg){
      float e = expf(gfv[reg]-mm);
      ss += e; nn += e*cvv[reg];
    }
    #pragma unroll
    for (int off=16; off<64; off<<=1){
      float mo = __shfl_xor(mm, off, 64);
      float so = __shfl_xor(ss, off, 64);
      float no = __shfl_xor(nn, off, 64);
      float mN = fmaxf(mm, mo);
      float ea = expf(mm-mN), eb = expf(mo-mN);
      ss = ss*ea + so*eb; nn = nn*ea + no*eb; mm = mN;
    }
    if (p==0){
      int ch = (n0 >> 4) & (NCH-1);
      int idx = (b*NCH + ch)*Hz + col;
      pm[idx]=mm; ps[idx]=ss; pn[idx]=nn;
    }
  }

  // 5-softmax + cell update
  float tdc = dc[b*Hz + col];
  float cnv[4];
  #pragma unroll
  for (int reg=0; reg<4; ++reg){
    int n2 = n0 + p*4 + reg;
    int l2 = n2 & 1023;
    float msk = smask[p*4+reg];
    float g0=acc[0][reg], g1=acc[1][reg], g2=acc[2][reg], g3=acc[3][reg], g4=acc[4][reg];
    float m5 = fmaxf(fmaxf(fmaxf(g0,g1),fmaxf(g2,g3)),g4);
    float e0=expf(g0-m5), e1=expf(g1-m5), e2=expf(g2-m5), e3=expf(g3-m5), e4=expf(g4-m5);
    float inv = 1.f/(e0+e1+e2+e3+e4);
    float cb = (l2==0)    ? 0.f : (float)cc[(size_t)(n2-1)*Hz + col];
    float ca = (l2==1023) ? 0.f : (float)cc[(size_t)(n2+1)*Hz + col];
    float em = (float)xe[(size_t)n2*Hz + col];
    float td = tdc*msk;
    float cnew = (cb*e0 + ca*e1 + em*e2 + td*e3 + cvv[reg]*e4)*inv;
    float hv = acc[5][reg]*tanhf(cnew);
    hsh[(p*4+reg)*260 + col] = hv*msk;
    cnv[reg] = cnew*msk;
  }
  __syncthreads();
  {
    int row = t>>6, c4 = lane*4;
    int n = n0 + row;
    const float* src = hsh + row*260 + c4;
    float v0=src[0], v1=src[1], v2=src[2], v3=src[3];
    if (last){
      *(float4*)(outf + (size_t)n*Hz + c4) = make_float4(v0,v1,v2,v3);
    } else {
      bf4_t o; o[0]=(__bf16)v0; o[1]=(__bf16)v1; o[2]=(__bf16)v2; o[3]=(__bf16)v3;
      *(bf4_t*)(hn + (size_t)n*Hz + c4) = o;
    }
  }
  __syncthreads();
  #pragma unroll
  for (int reg=0; reg<4; ++reg) hsh[(p*4+reg)*260 + col] = cnv[reg];
  __syncthreads();
  {
    int row = t>>6, c4 = lane*4;
    const float* src = hsh + row*260 + c4;
    bf4_t o; o[0]=(__bf16)src[0]; o[1]=(__bf16)src[1]; o[2]=(__bf16)src[2]; o[3]=(__bf16)src[3];
    *(bf4_t*)(cn + (size_t)(n0+row)*Hz + c4) = o;
  }
}

// ---- combine partials + gd/gi slots -> dc_new, dh_new ----
__global__ void k_soft_comb(const float* __restrict__ pm, const float* __restrict__ ps,
    const float* __restrict__ pn,
    const float* __restrict__ gd, const float* __restrict__ gi, const float* __restrict__ go,
    const float* __restrict__ tgg, const float* __restrict__ dc,
    float* __restrict__ dc_new, float* __restrict__ dh_new){
  int b = blockIdx.x, t = threadIdx.x;
  float vgd = gd[b*Hz+t], vgi = gi[b*Hz+t];
  float m = fmaxf(vgd, vgi);
  for (int ch=0; ch<NCH; ch++) m = fmaxf(m, pm[(b*NCH+ch)*Hz + t]);
  float ed = expf(vgd - m), ei = expf(vgi - m);
  float s  = ed + ei;
  float num = ed*dc[b*Hz+t] + ei*tgg[b*Hz+t];
  for (int ch=0; ch<NCH; ch++){
    int idx = (b*NCH+ch)*Hz + t;
    float e = expf(pm[idx] - m);
    s   += ps[idx]*e;
    num += pn[idx]*e;
  }
  float dcn = num/s;
  dc_new[b*Hz+t] = dcn;
  dh_new[b*Hz+t] = go[b*Hz+t]*tanhf(dcn);
}

extern "C" void kernel_launch(void* const* d_in, const int* in_sizes, int n_in,
                              void* d_out, int out_size, void* d_ws, size_t ws_size,
                              hipStream_t stream) {
  const float* word  = (const float*)d_in[0];
  const float* sent  = (const float*)d_in[1];
  const float* mask  = (const float*)d_in[2];
  const float* h0    = (const float*)d_in[3];
  const float* c0    = (const float*)d_in[4];
  const float* Wx_g  = (const float*)d_in[5];
  const float* Wh_g  = (const float*)d_in[6];
  const float* Wi_g  = (const float*)d_in[7];
  const float* Wd_g  = (const float*)d_in[8];
  const float* b_g   = (const float*)d_in[9];
  const float* gWx   = (const float*)d_in[10];
  const float* gWh   = (const float*)d_in[11];
  const float* gWg   = (const float*)d_in[12];
  const float* gb    = (const float*)d_in[13];
  const float* ln_a  = (const float*)d_in[14];
  const float* ln_b  = (const float*)d_in[15];
  float* out = (float*)d_out;

  char* wc = (char*)d_ws;
  __bf16* xe  = (__bf16*)wc;  wc += NHz*2;                         // 16.8 MB
  __bf16* h_a = (__bf16*)wc;  wc += NHz*2;                         // 16.8 MB
  __bf16* h_b = (__bf16*)wc;  wc += NHz*2;                         // 16.8 MB
  __bf16* c_a = (__bf16*)wc;  wc += NHz*2;                         // 16.8 MB
  __bf16* c_b = (__bf16*)wc;  wc += NHz*2;                         // 16.8 MB
  __bf16* pre = (__bf16*)wc;  wc += (size_t)(CHR/16)*NTC*256*2;    // 58.7 MB
  __bf16* Wp  = (__bf16*)wc;  wc += (size_t)1024*1792*2;           // 3.7 MB
  float* dh_a = (float*)wc;   wc += BHz*4;
  float* dh_b = (float*)wc;   wc += BHz*4;
  float* dc_a = (float*)wc;   wc += BHz*4;
  float* dc_b = (float*)wc;   wc += BHz*4;
  float* comb = (float*)wc;   wc += BHz*4;
  float* gd   = (float*)wc;   wc += BHz*4;
  float* gi_  = (float*)wc;   wc += BHz*4;
  float* go_  = (float*)wc;   wc += BHz*4;
  float* tgg  = (float*)wc;   wc += BHz*4;
  float* dhWd7 = (float*)wc;  wc += 7*BHz*4;
  float* pmean = (float*)wc;  wc += 8*BHz*4;
  float* pm = (float*)wc;     wc += (size_t)Bz*NCH*Hz*4;
  float* ps = (float*)wc;     wc += (size_t)Bz*NCH*Hz*4;
  float* pn = (float*)wc;     wc += (size_t)Bz*NCH*Hz*4;
  // total ~153 MB  (keep well under the ~208 MB proven-safe bound)

  // setup
  k_packW7<<<1024, 256, 0, stream>>>(Wx_g, Wh_g, Wi_g, gWh + 3*Hz*Hz, Wp);
  k_initb<<<4096, 256, 0, stream>>>(word, h0, c0, mask, xe, h_a, c_a);
  k_meanpb<<<dim3(Bz,8), 256, 0, stream>>>(h_a, pmean);
  k_comb8<<<Bz, 256, 0, stream>>>(pmean, dh_a);
  k_meanpb<<<dim3(Bz,8), 256, 0, stream>>>(c_a, pmean);
  k_comb8<<<Bz, 256, 0, stream>>>(pmean, dc_a);

  __bf16* hc=h_a; __bf16* hn=h_b;
  __bf16* cc=c_a; __bf16* cn=c_b;
  float* dhc=dh_a; float* dcc=dc_a; float* dhn=dh_b; float* dcn=dc_b;

  for (int layer=0; layer<NLAYERS; ++layer){
    k_meanpb<<<dim3(Bz,8), 256, 0, stream>>>(hc, pmean);
    k_comb8<<<Bz, 256, 0, stream>>>(pmean, comb);
    k_small<<<dim3(Bz,11), 256, 0, stream>>>(dhc, comb, sent, gWx, gWh, gWg, gb, Wd_g,
                                             ln_a, ln_b, gd, gi_, go_, tgg, dhWd7);
    int last = (layer == NLAYERS-1) ? 1 : 0;
    for (int chunk=0; chunk<Nz/CHR; ++chunk){
      int n_base = chunk*CHR;
      k_gemm<<<dim3(CHR/128, 14), 256, 0, stream>>>(xe, hc, Wp, pre, n_base);
      k_epi<<<CHR/16, 1024, 0, stream>>>(pre, xe, cc, mask, dhWd7, b_g, gb + 3*Hz,
                                         ln_a, ln_b, dcc, out, hn, cn, pm, ps, pn,
                                         n_base, last);
    }
    k_soft_comb<<<Bz, 256, 0, stream>>>(pm, ps, pn, gd, gi_, go_, tgg, dcc, dcn, dhn);
    __bf16* tb;
    tb=hc; hc=hn; hn=tb;
    tb=cc; cc=cn; cn=tb;
    float* tmp;
    tmp=dhc; dhc=dhn; dhn=tmp;
    tmp=dcc; dcc=dcn; dcn=tmp;
  }
  (void)in_sizes; (void)n_in; (void)out_size; (void)ws_size;
}